// Round 9
// baseline (880.617 us; speedup 1.0000x reference)
//
#include <hip/hip_runtime.h>
#include <hip/hip_bf16.h>

#define NTOK 1024     // tokens
#define TKN  2048     // expanded tokens (NTOK * topk)
#define NE   8        // experts
#define NRANK 4
#define IPR  1024     // intermediate per rank
#define HD   2048     // hidden
#define KD   4096     // NRANK * IPR
#define BM   128
#define BN   64
#define BK   64
#define KSPLIT 2
#define KPS  (KD / KSPLIT)   // 2048 K per split
#define NIT  (KPS / BK)      // 32 k-iterations per block (even)
#define XS   72              // LDS row stride in elements (144 B rows)
#define MAXTILES 24          // worst case sum ceil(c_e/128) = 23
#define NBL  (HD / BN)       // 32 n-blocks
#define NWG  (MAXTILES * NBL * KSPLIT)  // 1536 blocks, % 8 == 0

#define WS_YEXP_OFF 32768
#define WS_NEED ((size_t)WS_YEXP_OFF + (size_t)KSPLIT * TKN * HD * 4)

typedef __bf16 bf16x8 __attribute__((ext_vector_type(8)));
typedef float f32x4 __attribute__((ext_vector_type(4)));
typedef unsigned short u16x8 __attribute__((ext_vector_type(8)));

static __device__ inline unsigned short f2b(float f) {
  return __builtin_bit_cast(unsigned short, __float2bfloat16(f));
}

// ---------------- zero d_out (fallback path only) ----------------
__global__ __launch_bounds__(256) void zero_kernel(float* __restrict__ p) {
  size_t i = ((size_t)blockIdx.x * 256 + threadIdx.x) * 4;
  *reinterpret_cast<float4*>(p + i) = float4{0.f, 0.f, 0.f, 0.f};
}

// ---------------- routing: top-2 + softmax gates + expert grouping ----------------
__global__ void routing_kernel(const float* __restrict__ logits,
                               float* __restrict__ gate,
                               int* __restrict__ perm,
                               int* __restrict__ tile_e,
                               int* __restrict__ tile_r0,
                               int* __restrict__ tile_nr) {
  __shared__ int cnt[NE];
  __shared__ int cur[NE];
  const int tid = threadIdx.x;   // one thread per token, 1024 threads
  if (tid < NE) cnt[tid] = 0;
  __syncthreads();

  float l[NE];
#pragma unroll
  for (int e = 0; e < NE; ++e) l[e] = logits[tid * NE + e];

  float v0 = l[0]; int i0 = 0;
  float v1 = -3.4e38f; int i1 = 0;
#pragma unroll
  for (int e = 1; e < NE; ++e) {
    if (l[e] > v0) { v1 = v0; i1 = i0; v0 = l[e]; i0 = e; }
    else if (l[e] > v1) { v1 = l[e]; i1 = e; }
  }
  float e1  = expf(v1 - v0);      // v1 <= v0
  float inv = 1.0f / (1.0f + e1);
  gate[2 * tid]     = inv;        // slot 0 = argmax
  gate[2 * tid + 1] = e1 * inv;   // slot 1

  atomicAdd(&cnt[i0], 1);
  atomicAdd(&cnt[i1], 1);
  __syncthreads();

  if (tid == 0) {
    int run = 0, nt = 0;
    for (int e = 0; e < NE; ++e) {
      cur[e] = run;
      int c = cnt[e];
      for (int r0 = 0; r0 < c; r0 += BM) {
        tile_e[nt]  = e;
        tile_r0[nt] = run + r0;
        tile_nr[nt] = (c - r0 < BM) ? (c - r0) : BM;
        ++nt;
      }
      run += c;
    }
    for (; nt < MAXTILES; ++nt) tile_e[nt] = -1;
  }
  __syncthreads();

  int p0 = atomicAdd(&cur[i0], 1); perm[p0] = 2 * tid;
  int p1 = atomicAdd(&cur[i1], 1); perm[p1] = 2 * tid + 1;
}

// ---------------- grouped GEMM (K-split=2), 256 thr = 4 waves (2M x 2N) ----------------
// Depth-2 register prefetch: loads for tile t+2 issue at iter t, pack+LDS-write at
// iter t+2 -> load-to-use distance of 2 full iterations. Two NAMED reg banks,
// explicitly 2-unrolled loop (no runtime bank indexing -> stays in registers).
template <int WSP>
__global__ __launch_bounds__(256, 5) void gemm_kernel(
    const float* __restrict__ x,   // f32 [NRANK][TKN][IPR]
    const float* __restrict__ w,   // f32 [NRANK][NE][IPR][HD]
    const int* __restrict__ perm,
    const int* __restrict__ tile_e,
    const int* __restrict__ tile_r0,
    const int* __restrict__ tile_nr,
    const float* __restrict__ gate,
    float* __restrict__ yexp,
    float* __restrict__ out) {
  // Balanced XCD swizzle: chunk of NWG/8 consecutive sw per XCD; tile is the
  // FASTEST axis so data-dependent empty tiles spread evenly over XCDs.
  const int id = blockIdx.x;
  const int sw = (id & 7) * (NWG / 8) + (id >> 3);
  const int tile = sw % MAXTILES;
  const int rem  = sw / MAXTILES;
  const int nb   = rem & (NBL - 1);
  const int ksp  = rem >> 5;

  const int e = tile_e[tile];
  if (e < 0) return;
  const int row0 = tile_r0[tile];
  const int nr   = tile_nr[tile];
  const int n0   = nb * BN;
  const int kbase = ksp * KPS;

  __shared__ unsigned short Xs[BM][XS];   // bf16 bits, [m][k]  (18 KB)
  __shared__ unsigned short Ws[BN][XS];   // bf16 bits, transposed: [n][k] (9 KB)

  const int tid  = threadIdx.x;
  const int lane = tid & 63;
  const int wid  = tid >> 6;   // 0..3
  const int wr   = wid >> 1;   // 0..1 : 64-row stripe
  const int wc   = wid & 1;    // 0..1 : 32-col stripe

  // ---- X staging coords: 4 passes; 8 threads per row, 32 B (8 f32) each ----
  const int xr = tid >> 3;          // 0..31 (row within pass)
  const int xc = (tid & 7) << 3;    // k-offset 0,8,...,56
  int xtk[4];
#pragma unroll
  for (int p = 0; p < 4; ++p) {
    const int row = p * 32 + xr;
    xtk[p] = (row < nr) ? perm[row0 + row] : -1;
  }

  // ---- W staging coords: one n-column per thread, 16 k-values ----
  const int wn  = tid & 63;          // n within tile (consecutive lanes -> consecutive n)
  const int wkq = (tid >> 6) << 4;   // 0,16,32,48 (k-quarter per wave)

  // two raw-f32 prefetch banks (pack happens 2 iterations later)
  float4 xfA[4][2]; float wvA[16];
  float4 xfB[4][2]; float wvB[16];

#define LOADREGS(XF, WV, KT) do {                                                \
    const int r_  = (KT) >> 10;                                                  \
    const int i0_ = (KT) & 1023;                                                 \
    _Pragma("unroll")                                                            \
    for (int p_ = 0; p_ < 4; ++p_) {                                             \
      if (xtk[p_] >= 0) {                                                        \
        const float* sp_ = x + ((size_t)r_ * TKN + xtk[p_]) * IPR + i0_ + xc;    \
        XF[p_][0] = *reinterpret_cast<const float4*>(sp_);                       \
        XF[p_][1] = *reinterpret_cast<const float4*>(sp_ + 4);                   \
      } else {                                                                   \
        XF[p_][0] = float4{0.f, 0.f, 0.f, 0.f};                                  \
        XF[p_][1] = float4{0.f, 0.f, 0.f, 0.f};                                  \
      }                                                                          \
    }                                                                            \
    const float* wp_ = w + (((size_t)r_ * NE + e) * IPR + i0_ + wkq) * HD + n0 + wn; \
    _Pragma("unroll")                                                            \
    for (int j_ = 0; j_ < 16; ++j_) WV[j_] = wp_[(size_t)j_ * HD];               \
  } while (0)

#define PACKWRITE(XF, WV) do {                                                   \
    _Pragma("unroll")                                                            \
    for (int p_ = 0; p_ < 4; ++p_) {                                             \
      u16x8 v_;                                                                  \
      v_[0] = f2b(XF[p_][0].x); v_[1] = f2b(XF[p_][0].y);                        \
      v_[2] = f2b(XF[p_][0].z); v_[3] = f2b(XF[p_][0].w);                        \
      v_[4] = f2b(XF[p_][1].x); v_[5] = f2b(XF[p_][1].y);                        \
      v_[6] = f2b(XF[p_][1].z); v_[7] = f2b(XF[p_][1].w);                        \
      *reinterpret_cast<u16x8*>(&Xs[p_ * 32 + xr][xc]) = v_;                     \
    }                                                                            \
    u16x8 a_, b_;                                                                \
    a_[0] = f2b(WV[0]);  a_[1] = f2b(WV[1]);  a_[2] = f2b(WV[2]);                \
    a_[3] = f2b(WV[3]);  a_[4] = f2b(WV[4]);  a_[5] = f2b(WV[5]);                \
    a_[6] = f2b(WV[6]);  a_[7] = f2b(WV[7]);                                     \
    b_[0] = f2b(WV[8]);  b_[1] = f2b(WV[9]);  b_[2] = f2b(WV[10]);               \
    b_[3] = f2b(WV[11]); b_[4] = f2b(WV[12]); b_[5] = f2b(WV[13]);               \
    b_[6] = f2b(WV[14]); b_[7] = f2b(WV[15]);                                    \
    *reinterpret_cast<u16x8*>(&Ws[wn][wkq])     = a_;                            \
    *reinterpret_cast<u16x8*>(&Ws[wn][wkq + 8]) = b_;                            \
  } while (0)

  f32x4 acc[4][2];
#pragma unroll
  for (int a = 0; a < 4; ++a)
#pragma unroll
    for (int b = 0; b < 2; ++b) acc[a][b] = f32x4{0.f, 0.f, 0.f, 0.f};

  const int lrow = lane & 15;
  const int lk   = (lane >> 4) << 3;   // 0,8,16,24

#define COMPUTE() do {                                                           \
    _Pragma("unroll")                                                            \
    for (int ks_ = 0; ks_ < 2; ++ks_) {                                          \
      bf16x8 af_[4], bf_[2];                                                     \
      _Pragma("unroll")                                                          \
      for (int mi_ = 0; mi_ < 4; ++mi_)                                          \
        af_[mi_] = __builtin_bit_cast(bf16x8, *reinterpret_cast<const u16x8*>(   \
            &Xs[wr * 64 + mi_ * 16 + lrow][ks_ * 32 + lk]));                     \
      _Pragma("unroll")                                                          \
      for (int ni_ = 0; ni_ < 2; ++ni_)                                          \
        bf_[ni_] = __builtin_bit_cast(bf16x8, *reinterpret_cast<const u16x8*>(   \
            &Ws[wc * 32 + ni_ * 16 + lrow][ks_ * 32 + lk]));                     \
      _Pragma("unroll")                                                          \
      for (int mi_ = 0; mi_ < 4; ++mi_)                                          \
        _Pragma("unroll")                                                        \
        for (int ni_ = 0; ni_ < 2; ++ni_)                                        \
          acc[mi_][ni_] = __builtin_amdgcn_mfma_f32_16x16x32_bf16(               \
              af_[mi_], bf_[ni_], acc[mi_][ni_], 0, 0, 0);                       \
    }                                                                            \
  } while (0)

  // prologue: banks A,B <- tiles 0,1 (issued back-to-back, overlapped)
  LOADREGS(xfA, wvA, kbase);
  LOADREGS(xfB, wvB, kbase + BK);

  for (int t = 0; t < NIT; t += 2) {
    // ---- even iter: consume bank A (tile t) ----
    __syncthreads();                 // previous compute done; LDS free
    PACKWRITE(xfA, wvA);             // loads are 2 iters old -> no stall
    __syncthreads();                 // LDS ready
    if (t + 2 < NIT) LOADREGS(xfA, wvA, kbase + (t + 2) * BK);
    COMPUTE();

    // ---- odd iter: consume bank B (tile t+1) ----
    __syncthreads();
    PACKWRITE(xfB, wvB);
    __syncthreads();
    if (t + 3 < NIT) LOADREGS(xfB, wvB, kbase + (t + 3) * BK);
    COMPUTE();
  }

  // ---- epilogue ----
  const int mb = (lane >> 4) << 2;
#pragma unroll
  for (int mi = 0; mi < 4; ++mi) {
#pragma unroll
    for (int q = 0; q < 4; ++q) {
      const int m = wr * 64 + mi * 16 + mb + q;
      if (m < nr) {
        const int tk = perm[row0 + m];
        if (WSP) {
          float* dst = yexp + ((size_t)ksp * TKN + tk) * HD + n0 + wc * 32 + lrow;
#pragma unroll
          for (int ni = 0; ni < 2; ++ni)
            dst[ni * 16] = acc[mi][ni][q];
        } else {
          const float g = gate[tk];
          float* dst = out + (size_t)(tk >> 1) * HD + n0 + wc * 32 + lrow;
#pragma unroll
          for (int ni = 0; ni < 2; ++ni)
            atomicAdd(&dst[ni * 16], g * acc[mi][ni][q]);
        }
      }
    }
  }
#undef LOADREGS
#undef PACKWRITE
#undef COMPUTE
}

// ---------------- combine: out[t][h] = sum_s gate[2t+s] * sum_ksp yexp[ksp][2t+s][h] ----------------
__global__ __launch_bounds__(256) void combine_kernel(const float* __restrict__ yexp,
                                                      const float* __restrict__ gate,
                                                      float* __restrict__ out) {
  const int idx = blockIdx.x * 256 + threadIdx.x;  // 0 .. NTOK*HD/4-1
  const int t  = idx >> 9;            // HD/4 = 512 chunks per token
  const int h4 = (idx & 511) << 2;
  const float g0 = gate[2 * t];
  const float g1 = gate[2 * t + 1];

  const float* y00 = yexp + ((size_t)(2 * t)) * HD + h4;
  const float* y01 = yexp + ((size_t)(2 * t + 1)) * HD + h4;
  const float* y10 = yexp + ((size_t)TKN + 2 * t) * HD + h4;
  const float* y11 = yexp + ((size_t)TKN + 2 * t + 1) * HD + h4;
  float4 a0 = *reinterpret_cast<const float4*>(y00);
  float4 a1 = *reinterpret_cast<const float4*>(y01);
  float4 b0 = *reinterpret_cast<const float4*>(y10);
  float4 b1 = *reinterpret_cast<const float4*>(y11);

  float4 o;
  o.x = g0 * (a0.x + b0.x) + g1 * (a1.x + b1.x);
  o.y = g0 * (a0.y + b0.y) + g1 * (a1.y + b1.y);
  o.z = g0 * (a0.z + b0.z) + g1 * (a1.z + b1.z);
  o.w = g0 * (a0.w + b0.w) + g1 * (a1.w + b1.w);
  *reinterpret_cast<float4*>(out + (size_t)t * HD + h4) = o;
}

extern "C" void kernel_launch(void* const* d_in, const int* in_sizes, int n_in,
                              void* d_out, int out_size, void* d_ws, size_t ws_size,
                              hipStream_t stream) {
  const float* x      = (const float*)d_in[0];  // f32 (upcast from fp16)
  const float* w      = (const float*)d_in[1];  // f32 (upcast from fp16)
  const float* logits = (const float*)d_in[2];
  // d_in[3] = topk (constant 2), unused

  char* ws = (char*)d_ws;
  float* gate    = (float*)(ws + 0);          // TKN floats   (8 KB)
  int*   perm    = (int*)(ws + 8192);         // TKN ints     (8 KB)
  int*   tile_e  = (int*)(ws + 16384);        // MAXTILES ints
  int*   tile_r0 = (int*)(ws + 16384 + 256);
  int*   tile_nr = (int*)(ws + 16384 + 512);
  float* yexp    = (float*)(ws + WS_YEXP_OFF); // [KSPLIT][TKN][HD] f32 (33.6 MB)

  float* outf = (float*)d_out;                // f32 output [NTOK][HD]

  routing_kernel<<<1, 1024, 0, stream>>>(logits, gate, perm, tile_e, tile_r0, tile_nr);

  if (ws_size >= WS_NEED) {
    gemm_kernel<1><<<NWG, 256, 0, stream>>>(x, w, perm, tile_e, tile_r0, tile_nr,
                                            gate, yexp, outf);
    combine_kernel<<<(NTOK * HD / 4) / 256, 256, 0, stream>>>(yexp, gate, outf);
  } else {
    zero_kernel<<<(NTOK * HD / 4) / 256, 256, 0, stream>>>(outf);
    gemm_kernel<0><<<NWG, 256, 0, stream>>>(x, w, perm, tile_e, tile_r0, tile_nr,
                                            gate, yexp, outf);
  }
}

// Round 10
// 200.272 us; speedup vs baseline: 4.3971x; 4.3971x over previous
//
#include <hip/hip_runtime.h>
#include <hip/hip_bf16.h>

#define NTOK 1024     // tokens
#define TKN  2048     // expanded tokens (NTOK * topk)
#define NE   8        // experts
#define NRANK 4
#define IPR  1024     // intermediate per rank
#define HD   2048     // hidden
#define KD   4096     // NRANK * IPR
#define BM   128
#define BN   64
#define BK   64
#define KSPLIT 2
#define KPS  (KD / KSPLIT)   // 2048 K per split
#define NIT  (KPS / BK)      // 32 k-iterations per block (even)
#define XS   72              // LDS row stride in elements (144 B rows)
#define MAXTILES 24          // worst case sum ceil(c_e/128) = 23
#define NBL  (HD / BN)       // 32 n-blocks
#define NWG  (MAXTILES * NBL * KSPLIT)  // 1536 blocks, % 8 == 0

#define WS_YEXP_OFF 32768
#define WS_NEED ((size_t)WS_YEXP_OFF + (size_t)KSPLIT * TKN * HD * 4)

typedef __bf16 bf16x8 __attribute__((ext_vector_type(8)));
typedef float f32x4 __attribute__((ext_vector_type(4)));
typedef unsigned short u16x8 __attribute__((ext_vector_type(8)));

static __device__ inline unsigned short f2b(float f) {
  return __builtin_bit_cast(unsigned short, __float2bfloat16(f));
}

// Raw barrier: drain LDS ops only (lgkmcnt). Global loads stay in flight
// across the barrier (counted-vmcnt pipelining, T4). __syncthreads() would
// emit s_waitcnt vmcnt(0) and kill the 2-deep prefetch every iteration.
#define BAR() do {                                            \
    asm volatile("s_waitcnt lgkmcnt(0)" ::: "memory");        \
    __builtin_amdgcn_s_barrier();                             \
  } while (0)

// ---------------- zero d_out (fallback path only) ----------------
__global__ __launch_bounds__(256) void zero_kernel(float* __restrict__ p) {
  size_t i = ((size_t)blockIdx.x * 256 + threadIdx.x) * 4;
  *reinterpret_cast<float4*>(p + i) = float4{0.f, 0.f, 0.f, 0.f};
}

// ---------------- routing: top-2 + softmax gates + expert grouping ----------------
__global__ void routing_kernel(const float* __restrict__ logits,
                               float* __restrict__ gate,
                               int* __restrict__ perm,
                               int* __restrict__ tile_e,
                               int* __restrict__ tile_r0,
                               int* __restrict__ tile_nr) {
  __shared__ int cnt[NE];
  __shared__ int cur[NE];
  const int tid = threadIdx.x;   // one thread per token, 1024 threads
  if (tid < NE) cnt[tid] = 0;
  __syncthreads();

  float l[NE];
#pragma unroll
  for (int e = 0; e < NE; ++e) l[e] = logits[tid * NE + e];

  float v0 = l[0]; int i0 = 0;
  float v1 = -3.4e38f; int i1 = 0;
#pragma unroll
  for (int e = 1; e < NE; ++e) {
    if (l[e] > v0) { v1 = v0; i1 = i0; v0 = l[e]; i0 = e; }
    else if (l[e] > v1) { v1 = l[e]; i1 = e; }
  }
  float e1  = expf(v1 - v0);      // v1 <= v0
  float inv = 1.0f / (1.0f + e1);
  gate[2 * tid]     = inv;        // slot 0 = argmax
  gate[2 * tid + 1] = e1 * inv;   // slot 1

  atomicAdd(&cnt[i0], 1);
  atomicAdd(&cnt[i1], 1);
  __syncthreads();

  if (tid == 0) {
    int run = 0, nt = 0;
    for (int e = 0; e < NE; ++e) {
      cur[e] = run;
      int c = cnt[e];
      for (int r0 = 0; r0 < c; r0 += BM) {
        tile_e[nt]  = e;
        tile_r0[nt] = run + r0;
        tile_nr[nt] = (c - r0 < BM) ? (c - r0) : BM;
        ++nt;
      }
      run += c;
    }
    for (; nt < MAXTILES; ++nt) tile_e[nt] = -1;
  }
  __syncthreads();

  int p0 = atomicAdd(&cur[i0], 1); perm[p0] = 2 * tid;
  int p1 = atomicAdd(&cur[i1], 1); perm[p1] = 2 * tid + 1;
}

// ---------------- grouped GEMM (K-split=2), 256 thr = 4 waves (2M x 2N) ----------------
// Depth-2 register prefetch (two NAMED banks, 2-unrolled loop) + raw barriers:
// loads for tile t+2 issue at iter t, stay in flight across barriers, and are
// consumed (pack f32->bf16 -> LDS) at iter t+2. launch_bounds(256,2) gives the
// allocator room (~150-180 VGPR) so both banks live in registers -- r9's
// (256,5) cap forced them to scratch (VGPR=48, 1.5 GB spill traffic).
template <int WSP>
__global__ __launch_bounds__(256, 2) void gemm_kernel(
    const float* __restrict__ x,   // f32 [NRANK][TKN][IPR]
    const float* __restrict__ w,   // f32 [NRANK][NE][IPR][HD]
    const int* __restrict__ perm,
    const int* __restrict__ tile_e,
    const int* __restrict__ tile_r0,
    const int* __restrict__ tile_nr,
    const float* __restrict__ gate,
    float* __restrict__ yexp,
    float* __restrict__ out) {
  // Balanced XCD swizzle: chunk of NWG/8 consecutive sw per XCD; tile is the
  // FASTEST axis so data-dependent empty tiles spread evenly over XCDs.
  const int id = blockIdx.x;
  const int sw = (id & 7) * (NWG / 8) + (id >> 3);
  const int tile = sw % MAXTILES;
  const int rem  = sw / MAXTILES;
  const int nb   = rem & (NBL - 1);
  const int ksp  = rem >> 5;

  const int e = tile_e[tile];
  if (e < 0) return;
  const int row0 = tile_r0[tile];
  const int nr   = tile_nr[tile];
  const int n0   = nb * BN;
  const int kbase = ksp * KPS;

  __shared__ unsigned short Xs[BM][XS];   // bf16 bits, [m][k]  (18 KB)
  __shared__ unsigned short Ws[BN][XS];   // bf16 bits, transposed: [n][k] (9 KB)

  const int tid  = threadIdx.x;
  const int lane = tid & 63;
  const int wid  = tid >> 6;   // 0..3
  const int wr   = wid >> 1;   // 0..1 : 64-row stripe
  const int wc   = wid & 1;    // 0..1 : 32-col stripe

  // ---- X staging coords: 4 passes; 8 threads per row, 32 B (8 f32) each ----
  const int xr = tid >> 3;          // 0..31 (row within pass)
  const int xc = (tid & 7) << 3;    // k-offset 0,8,...,56
  int xtk[4];
#pragma unroll
  for (int p = 0; p < 4; ++p) {
    const int row = p * 32 + xr;
    xtk[p] = (row < nr) ? perm[row0 + row] : -1;
  }

  // ---- W staging coords: one n-column per thread, 16 k-values ----
  const int wn  = tid & 63;          // n within tile (consecutive lanes -> consecutive n)
  const int wkq = (tid >> 6) << 4;   // 0,16,32,48 (k-quarter per wave)

  // two raw-f32 prefetch banks (pack happens 2 iterations later)
  float4 xfA[4][2]; float wvA[16];
  float4 xfB[4][2]; float wvB[16];

#define LOADREGS(XF, WV, KT) do {                                                \
    const int r_  = (KT) >> 10;                                                  \
    const int i0_ = (KT) & 1023;                                                 \
    _Pragma("unroll")                                                            \
    for (int p_ = 0; p_ < 4; ++p_) {                                             \
      if (xtk[p_] >= 0) {                                                        \
        const float* sp_ = x + ((size_t)r_ * TKN + xtk[p_]) * IPR + i0_ + xc;    \
        XF[p_][0] = *reinterpret_cast<const float4*>(sp_);                       \
        XF[p_][1] = *reinterpret_cast<const float4*>(sp_ + 4);                   \
      } else {                                                                   \
        XF[p_][0] = float4{0.f, 0.f, 0.f, 0.f};                                  \
        XF[p_][1] = float4{0.f, 0.f, 0.f, 0.f};                                  \
      }                                                                          \
    }                                                                            \
    const float* wp_ = w + (((size_t)r_ * NE + e) * IPR + i0_ + wkq) * HD + n0 + wn; \
    _Pragma("unroll")                                                            \
    for (int j_ = 0; j_ < 16; ++j_) WV[j_] = wp_[(size_t)j_ * HD];               \
  } while (0)

#define PACKWRITE(XF, WV) do {                                                   \
    _Pragma("unroll")                                                            \
    for (int p_ = 0; p_ < 4; ++p_) {                                             \
      u16x8 v_;                                                                  \
      v_[0] = f2b(XF[p_][0].x); v_[1] = f2b(XF[p_][0].y);                        \
      v_[2] = f2b(XF[p_][0].z); v_[3] = f2b(XF[p_][0].w);                        \
      v_[4] = f2b(XF[p_][1].x); v_[5] = f2b(XF[p_][1].y);                        \
      v_[6] = f2b(XF[p_][1].z); v_[7] = f2b(XF[p_][1].w);                        \
      *reinterpret_cast<u16x8*>(&Xs[p_ * 32 + xr][xc]) = v_;                     \
    }                                                                            \
    u16x8 a_, b_;                                                                \
    a_[0] = f2b(WV[0]);  a_[1] = f2b(WV[1]);  a_[2] = f2b(WV[2]);                \
    a_[3] = f2b(WV[3]);  a_[4] = f2b(WV[4]);  a_[5] = f2b(WV[5]);                \
    a_[6] = f2b(WV[6]);  a_[7] = f2b(WV[7]);                                     \
    b_[0] = f2b(WV[8]);  b_[1] = f2b(WV[9]);  b_[2] = f2b(WV[10]);               \
    b_[3] = f2b(WV[11]); b_[4] = f2b(WV[12]); b_[5] = f2b(WV[13]);               \
    b_[6] = f2b(WV[14]); b_[7] = f2b(WV[15]);                                    \
    *reinterpret_cast<u16x8*>(&Ws[wn][wkq])     = a_;                            \
    *reinterpret_cast<u16x8*>(&Ws[wn][wkq + 8]) = b_;                            \
  } while (0)

  f32x4 acc[4][2];
#pragma unroll
  for (int a = 0; a < 4; ++a)
#pragma unroll
    for (int b = 0; b < 2; ++b) acc[a][b] = f32x4{0.f, 0.f, 0.f, 0.f};

  const int lrow = lane & 15;
  const int lk   = (lane >> 4) << 3;   // 0,8,16,24

#define COMPUTE() do {                                                           \
    _Pragma("unroll")                                                            \
    for (int ks_ = 0; ks_ < 2; ++ks_) {                                          \
      bf16x8 af_[4], bf_[2];                                                     \
      _Pragma("unroll")                                                          \
      for (int mi_ = 0; mi_ < 4; ++mi_)                                          \
        af_[mi_] = __builtin_bit_cast(bf16x8, *reinterpret_cast<const u16x8*>(   \
            &Xs[wr * 64 + mi_ * 16 + lrow][ks_ * 32 + lk]));                     \
      _Pragma("unroll")                                                          \
      for (int ni_ = 0; ni_ < 2; ++ni_)                                          \
        bf_[ni_] = __builtin_bit_cast(bf16x8, *reinterpret_cast<const u16x8*>(   \
            &Ws[wc * 32 + ni_ * 16 + lrow][ks_ * 32 + lk]));                     \
      _Pragma("unroll")                                                          \
      for (int mi_ = 0; mi_ < 4; ++mi_)                                          \
        _Pragma("unroll")                                                        \
        for (int ni_ = 0; ni_ < 2; ++ni_)                                        \
          acc[mi_][ni_] = __builtin_amdgcn_mfma_f32_16x16x32_bf16(               \
              af_[mi_], bf_[ni_], acc[mi_][ni_], 0, 0, 0);                       \
    }                                                                            \
  } while (0)

  // prologue: banks A,B <- tiles 0,1 (issued back-to-back, overlapped)
  LOADREGS(xfA, wvA, kbase);
  LOADREGS(xfB, wvB, kbase + BK);

  for (int t = 0; t < NIT; t += 2) {
    // ---- even iter: consume bank A (tile t) ----
    BAR();                           // previous compute's LDS reads drained
    PACKWRITE(xfA, wvA);             // waits (counted vmcnt) on 2-iter-old loads
    BAR();                           // ds_writes visible to all waves
    if (t + 2 < NIT) LOADREGS(xfA, wvA, kbase + (t + 2) * BK);
    COMPUTE();

    // ---- odd iter: consume bank B (tile t+1) ----
    BAR();
    PACKWRITE(xfB, wvB);
    BAR();
    if (t + 3 < NIT) LOADREGS(xfB, wvB, kbase + (t + 3) * BK);
    COMPUTE();
  }

  // ---- epilogue ----
  const int mb = (lane >> 4) << 2;
#pragma unroll
  for (int mi = 0; mi < 4; ++mi) {
#pragma unroll
    for (int q = 0; q < 4; ++q) {
      const int m = wr * 64 + mi * 16 + mb + q;
      if (m < nr) {
        const int tk = perm[row0 + m];
        if (WSP) {
          float* dst = yexp + ((size_t)ksp * TKN + tk) * HD + n0 + wc * 32 + lrow;
#pragma unroll
          for (int ni = 0; ni < 2; ++ni)
            dst[ni * 16] = acc[mi][ni][q];
        } else {
          const float g = gate[tk];
          float* dst = out + (size_t)(tk >> 1) * HD + n0 + wc * 32 + lrow;
#pragma unroll
          for (int ni = 0; ni < 2; ++ni)
            atomicAdd(&dst[ni * 16], g * acc[mi][ni][q]);
        }
      }
    }
  }
#undef LOADREGS
#undef PACKWRITE
#undef COMPUTE
}

// ---------------- combine: out[t][h] = sum_s gate[2t+s] * sum_ksp yexp[ksp][2t+s][h] ----------------
__global__ __launch_bounds__(256) void combine_kernel(const float* __restrict__ yexp,
                                                      const float* __restrict__ gate,
                                                      float* __restrict__ out) {
  const int idx = blockIdx.x * 256 + threadIdx.x;  // 0 .. NTOK*HD/4-1
  const int t  = idx >> 9;            // HD/4 = 512 chunks per token
  const int h4 = (idx & 511) << 2;
  const float g0 = gate[2 * t];
  const float g1 = gate[2 * t + 1];

  const float* y00 = yexp + ((size_t)(2 * t)) * HD + h4;
  const float* y01 = yexp + ((size_t)(2 * t + 1)) * HD + h4;
  const float* y10 = yexp + ((size_t)TKN + 2 * t) * HD + h4;
  const float* y11 = yexp + ((size_t)TKN + 2 * t + 1) * HD + h4;
  float4 a0 = *reinterpret_cast<const float4*>(y00);
  float4 a1 = *reinterpret_cast<const float4*>(y01);
  float4 b0 = *reinterpret_cast<const float4*>(y10);
  float4 b1 = *reinterpret_cast<const float4*>(y11);

  float4 o;
  o.x = g0 * (a0.x + b0.x) + g1 * (a1.x + b1.x);
  o.y = g0 * (a0.y + b0.y) + g1 * (a1.y + b1.y);
  o.z = g0 * (a0.z + b0.z) + g1 * (a1.z + b1.z);
  o.w = g0 * (a0.w + b0.w) + g1 * (a1.w + b1.w);
  *reinterpret_cast<float4*>(out + (size_t)t * HD + h4) = o;
}

extern "C" void kernel_launch(void* const* d_in, const int* in_sizes, int n_in,
                              void* d_out, int out_size, void* d_ws, size_t ws_size,
                              hipStream_t stream) {
  const float* x      = (const float*)d_in[0];  // f32 (upcast from fp16)
  const float* w      = (const float*)d_in[1];  // f32 (upcast from fp16)
  const float* logits = (const float*)d_in[2];
  // d_in[3] = topk (constant 2), unused

  char* ws = (char*)d_ws;
  float* gate    = (float*)(ws + 0);          // TKN floats   (8 KB)
  int*   perm    = (int*)(ws + 8192);         // TKN ints     (8 KB)
  int*   tile_e  = (int*)(ws + 16384);        // MAXTILES ints
  int*   tile_r0 = (int*)(ws + 16384 + 256);
  int*   tile_nr = (int*)(ws + 16384 + 512);
  float* yexp    = (float*)(ws + WS_YEXP_OFF); // [KSPLIT][TKN][HD] f32 (33.6 MB)

  float* outf = (float*)d_out;                // f32 output [NTOK][HD]

  routing_kernel<<<1, 1024, 0, stream>>>(logits, gate, perm, tile_e, tile_r0, tile_nr);

  if (ws_size >= WS_NEED) {
    gemm_kernel<1><<<NWG, 256, 0, stream>>>(x, w, perm, tile_e, tile_r0, tile_nr,
                                            gate, yexp, outf);
    combine_kernel<<<(NTOK * HD / 4) / 256, 256, 0, stream>>>(yexp, gate, outf);
  } else {
    zero_kernel<<<(NTOK * HD / 4) / 256, 256, 0, stream>>>(outf);
    gemm_kernel<0><<<NWG, 256, 0, stream>>>(x, w, perm, tile_e, tile_r0, tile_nr,
                                            gate, yexp, outf);
  }
}

// Round 11
// 199.654 us; speedup vs baseline: 4.4107x; 1.0031x over previous
//
#include <hip/hip_runtime.h>
#include <hip/hip_bf16.h>

#define NTOK 1024     // tokens
#define TKN  2048     // expanded tokens (NTOK * topk)
#define NE   8        // experts
#define NRANK 4
#define IPR  1024     // intermediate per rank
#define HD   2048     // hidden
#define KD   4096     // NRANK * IPR
#define BM   128
#define BN   64
#define BK   64
#define KSPLIT 2
#define KPS  (KD / KSPLIT)   // 2048 K per split
#define NIT  (KPS / BK)      // 32 k-iterations per block (even)
#define XS   72              // LDS row stride in elements (144 B rows)
#define MAXTILES 24          // worst case sum ceil(c_e/128) = 23
#define NBL  (HD / BN)       // 32 n-blocks
#define NWG  (MAXTILES * NBL * KSPLIT)  // 1536 blocks, % 8 == 0

#define WS_YEXP_OFF 32768
#define WS_NEED ((size_t)WS_YEXP_OFF + (size_t)KSPLIT * TKN * HD * 4)

typedef __bf16 bf16x8 __attribute__((ext_vector_type(8)));
typedef float f32x4 __attribute__((ext_vector_type(4)));
typedef unsigned short u16x8 __attribute__((ext_vector_type(8)));

static __device__ inline unsigned short f2b(float f) {
  return __builtin_bit_cast(unsigned short, __float2bfloat16(f));
}

// Barrier WITHOUT a memory clobber: a "memory" clobber (or __syncthreads)
// forces the compiler to drain vmcnt(0) before the barrier, killing the
// register prefetch every iteration (rounds 2-10's invariant ~200us).
// Order is pinned with sched_barrier(0) (compile-time fence, no waitcnt);
// lgkmcnt(0) drains LDS ops only. Global loads stay in flight across the
// barrier; the compiler's dependence tracking emits counted vmcnt(N) at the
// point the prefetched registers are actually consumed (T4, rule #18).
#define BAR() do {                                            \
    __builtin_amdgcn_sched_barrier(0);                        \
    asm volatile("s_waitcnt lgkmcnt(0)");                     \
    __builtin_amdgcn_sched_barrier(0);                        \
    __builtin_amdgcn_s_barrier();                             \
    __builtin_amdgcn_sched_barrier(0);                        \
  } while (0)

// ---------------- zero d_out (fallback path only) ----------------
__global__ __launch_bounds__(256) void zero_kernel(float* __restrict__ p) {
  size_t i = ((size_t)blockIdx.x * 256 + threadIdx.x) * 4;
  *reinterpret_cast<float4*>(p + i) = float4{0.f, 0.f, 0.f, 0.f};
}

// ---------------- routing: top-2 + softmax gates + expert grouping ----------------
__global__ void routing_kernel(const float* __restrict__ logits,
                               float* __restrict__ gate,
                               int* __restrict__ perm,
                               int* __restrict__ tile_e,
                               int* __restrict__ tile_r0,
                               int* __restrict__ tile_nr) {
  __shared__ int cnt[NE];
  __shared__ int cur[NE];
  const int tid = threadIdx.x;   // one thread per token, 1024 threads
  if (tid < NE) cnt[tid] = 0;
  __syncthreads();

  float l[NE];
#pragma unroll
  for (int e = 0; e < NE; ++e) l[e] = logits[tid * NE + e];

  float v0 = l[0]; int i0 = 0;
  float v1 = -3.4e38f; int i1 = 0;
#pragma unroll
  for (int e = 1; e < NE; ++e) {
    if (l[e] > v0) { v1 = v0; i1 = i0; v0 = l[e]; i0 = e; }
    else if (l[e] > v1) { v1 = l[e]; i1 = e; }
  }
  float e1  = expf(v1 - v0);      // v1 <= v0
  float inv = 1.0f / (1.0f + e1);
  gate[2 * tid]     = inv;        // slot 0 = argmax
  gate[2 * tid + 1] = e1 * inv;   // slot 1

  atomicAdd(&cnt[i0], 1);
  atomicAdd(&cnt[i1], 1);
  __syncthreads();

  if (tid == 0) {
    int run = 0, nt = 0;
    for (int e = 0; e < NE; ++e) {
      cur[e] = run;
      int c = cnt[e];
      for (int r0 = 0; r0 < c; r0 += BM) {
        tile_e[nt]  = e;
        tile_r0[nt] = run + r0;
        tile_nr[nt] = (c - r0 < BM) ? (c - r0) : BM;
        ++nt;
      }
      run += c;
    }
    for (; nt < MAXTILES; ++nt) tile_e[nt] = -1;
  }
  __syncthreads();

  int p0 = atomicAdd(&cur[i0], 1); perm[p0] = 2 * tid;
  int p1 = atomicAdd(&cur[i1], 1); perm[p1] = 2 * tid + 1;
}

// ---------------- grouped GEMM (K-split=2), 256 thr = 4 waves (2M x 2N) ----------------
// Depth-2 register prefetch (two NAMED banks, 2-unrolled loop) + clobber-free
// barriers: loads for tile t+2 issue at iter t, STAY IN FLIGHT across the
// barriers, and are consumed (counted vmcnt) at iter t+2.
template <int WSP>
__global__ __launch_bounds__(256, 2) void gemm_kernel(
    const float* __restrict__ x,   // f32 [NRANK][TKN][IPR]
    const float* __restrict__ w,   // f32 [NRANK][NE][IPR][HD]
    const int* __restrict__ perm,
    const int* __restrict__ tile_e,
    const int* __restrict__ tile_r0,
    const int* __restrict__ tile_nr,
    const float* __restrict__ gate,
    float* __restrict__ yexp,
    float* __restrict__ out) {
  // Balanced XCD swizzle: chunk of NWG/8 consecutive sw per XCD; tile is the
  // FASTEST axis so data-dependent empty tiles spread evenly over XCDs.
  const int id = blockIdx.x;
  const int sw = (id & 7) * (NWG / 8) + (id >> 3);
  const int tile = sw % MAXTILES;
  const int rem  = sw / MAXTILES;
  const int nb   = rem & (NBL - 1);
  const int ksp  = rem >> 5;

  const int e = tile_e[tile];
  if (e < 0) return;
  const int row0 = tile_r0[tile];
  const int nr   = tile_nr[tile];
  const int n0   = nb * BN;
  const int kbase = ksp * KPS;

  __shared__ unsigned short Xs[BM][XS];   // bf16 bits, [m][k]  (18 KB)
  __shared__ unsigned short Ws[BN][XS];   // bf16 bits, transposed: [n][k] (9 KB)

  const int tid  = threadIdx.x;
  const int lane = tid & 63;
  const int wid  = tid >> 6;   // 0..3
  const int wr   = wid >> 1;   // 0..1 : 64-row stripe
  const int wc   = wid & 1;    // 0..1 : 32-col stripe

  // ---- X staging coords: 4 passes; 8 threads per row, 32 B (8 f32) each ----
  const int xr = tid >> 3;          // 0..31 (row within pass)
  const int xc = (tid & 7) << 3;    // k-offset 0,8,...,56
  int xtk[4];
#pragma unroll
  for (int p = 0; p < 4; ++p) {
    const int row = p * 32 + xr;
    xtk[p] = (row < nr) ? perm[row0 + row] : -1;
  }

  // ---- W staging coords: one n-column per thread, 16 k-values ----
  const int wn  = tid & 63;          // n within tile (consecutive lanes -> consecutive n)
  const int wkq = (tid >> 6) << 4;   // 0,16,32,48 (k-quarter per wave)

  // two raw-f32 prefetch banks (pack happens 2 iterations later)
  float4 xfA[4][2]; float wvA[16];
  float4 xfB[4][2]; float wvB[16];

#define LOADREGS(XF, WV, KT) do {                                                \
    const int r_  = (KT) >> 10;                                                  \
    const int i0_ = (KT) & 1023;                                                 \
    _Pragma("unroll")                                                            \
    for (int p_ = 0; p_ < 4; ++p_) {                                             \
      if (xtk[p_] >= 0) {                                                        \
        const float* sp_ = x + ((size_t)r_ * TKN + xtk[p_]) * IPR + i0_ + xc;    \
        XF[p_][0] = *reinterpret_cast<const float4*>(sp_);                       \
        XF[p_][1] = *reinterpret_cast<const float4*>(sp_ + 4);                   \
      } else {                                                                   \
        XF[p_][0] = float4{0.f, 0.f, 0.f, 0.f};                                  \
        XF[p_][1] = float4{0.f, 0.f, 0.f, 0.f};                                  \
      }                                                                          \
    }                                                                            \
    const float* wp_ = w + (((size_t)r_ * NE + e) * IPR + i0_ + wkq) * HD + n0 + wn; \
    _Pragma("unroll")                                                            \
    for (int j_ = 0; j_ < 16; ++j_) WV[j_] = wp_[(size_t)j_ * HD];               \
  } while (0)

#define PACKWRITE(XF, WV) do {                                                   \
    _Pragma("unroll")                                                            \
    for (int p_ = 0; p_ < 4; ++p_) {                                             \
      u16x8 v_;                                                                  \
      v_[0] = f2b(XF[p_][0].x); v_[1] = f2b(XF[p_][0].y);                        \
      v_[2] = f2b(XF[p_][0].z); v_[3] = f2b(XF[p_][0].w);                        \
      v_[4] = f2b(XF[p_][1].x); v_[5] = f2b(XF[p_][1].y);                        \
      v_[6] = f2b(XF[p_][1].z); v_[7] = f2b(XF[p_][1].w);                        \
      *reinterpret_cast<u16x8*>(&Xs[p_ * 32 + xr][xc]) = v_;                     \
    }                                                                            \
    u16x8 a_, b_;                                                                \
    a_[0] = f2b(WV[0]);  a_[1] = f2b(WV[1]);  a_[2] = f2b(WV[2]);                \
    a_[3] = f2b(WV[3]);  a_[4] = f2b(WV[4]);  a_[5] = f2b(WV[5]);                \
    a_[6] = f2b(WV[6]);  a_[7] = f2b(WV[7]);                                     \
    b_[0] = f2b(WV[8]);  b_[1] = f2b(WV[9]);  b_[2] = f2b(WV[10]);               \
    b_[3] = f2b(WV[11]); b_[4] = f2b(WV[12]); b_[5] = f2b(WV[13]);               \
    b_[6] = f2b(WV[14]); b_[7] = f2b(WV[15]);                                    \
    *reinterpret_cast<u16x8*>(&Ws[wn][wkq])     = a_;                            \
    *reinterpret_cast<u16x8*>(&Ws[wn][wkq + 8]) = b_;                            \
  } while (0)

  f32x4 acc[4][2];
#pragma unroll
  for (int a = 0; a < 4; ++a)
#pragma unroll
    for (int b = 0; b < 2; ++b) acc[a][b] = f32x4{0.f, 0.f, 0.f, 0.f};

  const int lrow = lane & 15;
  const int lk   = (lane >> 4) << 3;   // 0,8,16,24

#define COMPUTE() do {                                                           \
    _Pragma("unroll")                                                            \
    for (int ks_ = 0; ks_ < 2; ++ks_) {                                          \
      bf16x8 af_[4], bf_[2];                                                     \
      _Pragma("unroll")                                                          \
      for (int mi_ = 0; mi_ < 4; ++mi_)                                          \
        af_[mi_] = __builtin_bit_cast(bf16x8, *reinterpret_cast<const u16x8*>(   \
            &Xs[wr * 64 + mi_ * 16 + lrow][ks_ * 32 + lk]));                     \
      _Pragma("unroll")                                                          \
      for (int ni_ = 0; ni_ < 2; ++ni_)                                          \
        bf_[ni_] = __builtin_bit_cast(bf16x8, *reinterpret_cast<const u16x8*>(   \
            &Ws[wc * 32 + ni_ * 16 + lrow][ks_ * 32 + lk]));                     \
      _Pragma("unroll")                                                          \
      for (int mi_ = 0; mi_ < 4; ++mi_)                                          \
        _Pragma("unroll")                                                        \
        for (int ni_ = 0; ni_ < 2; ++ni_)                                        \
          acc[mi_][ni_] = __builtin_amdgcn_mfma_f32_16x16x32_bf16(               \
              af_[mi_], bf_[ni_], acc[mi_][ni_], 0, 0, 0);                       \
    }                                                                            \
  } while (0)

  // prologue: banks A,B <- tiles 0,1 (issued back-to-back, overlapped)
  LOADREGS(xfA, wvA, kbase);
  LOADREGS(xfB, wvB, kbase + BK);

  for (int t = 0; t < NIT; t += 2) {
    // ---- even iter: consume bank A (tile t) ----
    BAR();                           // LDS free (lgkm only; vmem stays in flight)
    PACKWRITE(xfA, wvA);             // counted vmcnt: waits A only (B outstanding)
    BAR();                           // ds_writes visible
    if (t + 2 < NIT) LOADREGS(xfA, wvA, kbase + (t + 2) * BK);
    COMPUTE();

    // ---- odd iter: consume bank B (tile t+1) ----
    BAR();
    PACKWRITE(xfB, wvB);
    BAR();
    if (t + 3 < NIT) LOADREGS(xfB, wvB, kbase + (t + 3) * BK);
    COMPUTE();
  }

  // ---- epilogue ----
  const int mb = (lane >> 4) << 2;
#pragma unroll
  for (int mi = 0; mi < 4; ++mi) {
#pragma unroll
    for (int q = 0; q < 4; ++q) {
      const int m = wr * 64 + mi * 16 + mb + q;
      if (m < nr) {
        const int tk = perm[row0 + m];
        if (WSP) {
          float* dst = yexp + ((size_t)ksp * TKN + tk) * HD + n0 + wc * 32 + lrow;
#pragma unroll
          for (int ni = 0; ni < 2; ++ni)
            dst[ni * 16] = acc[mi][ni][q];
        } else {
          const float g = gate[tk];
          float* dst = out + (size_t)(tk >> 1) * HD + n0 + wc * 32 + lrow;
#pragma unroll
          for (int ni = 0; ni < 2; ++ni)
            atomicAdd(&dst[ni * 16], g * acc[mi][ni][q]);
        }
      }
    }
  }
#undef LOADREGS
#undef PACKWRITE
#undef COMPUTE
}

// ---------------- combine: out[t][h] = sum_s gate[2t+s] * sum_ksp yexp[ksp][2t+s][h] ----------------
__global__ __launch_bounds__(256) void combine_kernel(const float* __restrict__ yexp,
                                                      const float* __restrict__ gate,
                                                      float* __restrict__ out) {
  const int idx = blockIdx.x * 256 + threadIdx.x;  // 0 .. NTOK*HD/4-1
  const int t  = idx >> 9;            // HD/4 = 512 chunks per token
  const int h4 = (idx & 511) << 2;
  const float g0 = gate[2 * t];
  const float g1 = gate[2 * t + 1];

  const float* y00 = yexp + ((size_t)(2 * t)) * HD + h4;
  const float* y01 = yexp + ((size_t)(2 * t + 1)) * HD + h4;
  const float* y10 = yexp + ((size_t)TKN + 2 * t) * HD + h4;
  const float* y11 = yexp + ((size_t)TKN + 2 * t + 1) * HD + h4;
  float4 a0 = *reinterpret_cast<const float4*>(y00);
  float4 a1 = *reinterpret_cast<const float4*>(y01);
  float4 b0 = *reinterpret_cast<const float4*>(y10);
  float4 b1 = *reinterpret_cast<const float4*>(y11);

  float4 o;
  o.x = g0 * (a0.x + b0.x) + g1 * (a1.x + b1.x);
  o.y = g0 * (a0.y + b0.y) + g1 * (a1.y + b1.y);
  o.z = g0 * (a0.z + b0.z) + g1 * (a1.z + b1.z);
  o.w = g0 * (a0.w + b0.w) + g1 * (a1.w + b1.w);
  *reinterpret_cast<float4*>(out + (size_t)t * HD + h4) = o;
}

extern "C" void kernel_launch(void* const* d_in, const int* in_sizes, int n_in,
                              void* d_out, int out_size, void* d_ws, size_t ws_size,
                              hipStream_t stream) {
  const float* x      = (const float*)d_in[0];  // f32 (upcast from fp16)
  const float* w      = (const float*)d_in[1];  // f32 (upcast from fp16)
  const float* logits = (const float*)d_in[2];
  // d_in[3] = topk (constant 2), unused

  char* ws = (char*)d_ws;
  float* gate    = (float*)(ws + 0);          // TKN floats   (8 KB)
  int*   perm    = (int*)(ws + 8192);         // TKN ints     (8 KB)
  int*   tile_e  = (int*)(ws + 16384);        // MAXTILES ints
  int*   tile_r0 = (int*)(ws + 16384 + 256);
  int*   tile_nr = (int*)(ws + 16384 + 512);
  float* yexp    = (float*)(ws + WS_YEXP_OFF); // [KSPLIT][TKN][HD] f32 (33.6 MB)

  float* outf = (float*)d_out;                // f32 output [NTOK][HD]

  routing_kernel<<<1, 1024, 0, stream>>>(logits, gate, perm, tile_e, tile_r0, tile_nr);

  if (ws_size >= WS_NEED) {
    gemm_kernel<1><<<NWG, 256, 0, stream>>>(x, w, perm, tile_e, tile_r0, tile_nr,
                                            gate, yexp, outf);
    combine_kernel<<<(NTOK * HD / 4) / 256, 256, 0, stream>>>(yexp, gate, outf);
  } else {
    zero_kernel<<<(NTOK * HD / 4) / 256, 256, 0, stream>>>(outf);
    gemm_kernel<0><<<NWG, 256, 0, stream>>>(x, w, perm, tile_e, tile_r0, tile_nr,
                                            gate, yexp, outf);
  }
}

// Round 12
// 169.859 us; speedup vs baseline: 5.1844x; 1.1754x over previous
//
#include <hip/hip_runtime.h>
#include <hip/hip_bf16.h>

#define NTOK 1024     // tokens
#define TKN  2048     // expanded tokens (NTOK * topk)
#define NE   8        // experts
#define NRANK 4
#define IPR  1024     // intermediate per rank
#define HD   2048     // hidden
#define KD   4096     // NRANK * IPR
#define BM   128
#define BN   64
#define BK   64
#define NIT  (KD / BK)   // 64 k-iterations
#define XS   72          // LDS row stride in elements (144 B rows)
#define MAXTILES 24      // worst case sum ceil(c_e/128) = 23
#define NBL  (HD / BN)   // 32 n-blocks
#define NWG  (MAXTILES * NBL)  // 768 blocks, % 8 == 0

typedef __bf16 bf16x8 __attribute__((ext_vector_type(8)));
typedef float f32x4 __attribute__((ext_vector_type(4)));
typedef unsigned short u16x8 __attribute__((ext_vector_type(8)));

static __device__ inline unsigned short f2b(float f) {
  return __builtin_bit_cast(unsigned short, __float2bfloat16(f));
}

// Clobber-free barrier (r11-verified correct): drains LDS ops only; global
// loads stay in flight. sched_barrier(0) pins ordering without forcing the
// compiler to treat the asm as touching memory.
#define BAR() do {                                            \
    __builtin_amdgcn_sched_barrier(0);                        \
    asm volatile("s_waitcnt lgkmcnt(0)");                     \
    __builtin_amdgcn_sched_barrier(0);                        \
    __builtin_amdgcn_s_barrier();                             \
    __builtin_amdgcn_sched_barrier(0);                        \
  } while (0)

// ---------------- zero d_out (harness doesn't re-zero between replays) ----------------
__global__ __launch_bounds__(256) void zero_kernel(float* __restrict__ p) {
  size_t i = ((size_t)blockIdx.x * 256 + threadIdx.x) * 4;
  *reinterpret_cast<float4*>(p + i) = float4{0.f, 0.f, 0.f, 0.f};
}

// ---------------- routing: top-2 + softmax gates + expert grouping ----------------
__global__ void routing_kernel(const float* __restrict__ logits,
                               float* __restrict__ gate,
                               int* __restrict__ perm,
                               int* __restrict__ tile_e,
                               int* __restrict__ tile_r0,
                               int* __restrict__ tile_nr) {
  __shared__ int cnt[NE];
  __shared__ int cur[NE];
  const int tid = threadIdx.x;   // one thread per token, 1024 threads
  if (tid < NE) cnt[tid] = 0;
  __syncthreads();

  float l[NE];
#pragma unroll
  for (int e = 0; e < NE; ++e) l[e] = logits[tid * NE + e];

  float v0 = l[0]; int i0 = 0;
  float v1 = -3.4e38f; int i1 = 0;
#pragma unroll
  for (int e = 1; e < NE; ++e) {
    if (l[e] > v0) { v1 = v0; i1 = i0; v0 = l[e]; i0 = e; }
    else if (l[e] > v1) { v1 = l[e]; i1 = e; }
  }
  float e1  = expf(v1 - v0);      // v1 <= v0
  float inv = 1.0f / (1.0f + e1);
  gate[2 * tid]     = inv;        // slot 0 = argmax
  gate[2 * tid + 1] = e1 * inv;   // slot 1

  atomicAdd(&cnt[i0], 1);
  atomicAdd(&cnt[i1], 1);
  __syncthreads();

  if (tid == 0) {
    int run = 0, nt = 0;
    for (int e = 0; e < NE; ++e) {
      cur[e] = run;
      int c = cnt[e];
      for (int r0 = 0; r0 < c; r0 += BM) {
        tile_e[nt]  = e;
        tile_r0[nt] = run + r0;
        tile_nr[nt] = (c - r0 < BM) ? (c - r0) : BM;
        ++nt;
      }
      run += c;
    }
    for (; nt < MAXTILES; ++nt) tile_e[nt] = -1;
  }
  __syncthreads();

  int p0 = atomicAdd(&cur[i0], 1); perm[p0] = 2 * tid;
  int p1 = atomicAdd(&cur[i1], 1); perm[p1] = 2 * tid + 1;
}

// ---------------- grouped GEMM (r4 structure): out[tk>>1][h] += gate[tk]*(x[tk].W_e)[h] ----------------
// 256 thr = 4 waves (2M x 2N), BM=128, BN=64, full K per block (no split).
// Depth-1 register prefetch; clobber-free barriers; atomic f32 epilogue
// (exactly 2 adds/element -> deterministic).
__global__ __launch_bounds__(256, 3) void gemm_kernel(
    const float* __restrict__ x,   // f32 [NRANK][TKN][IPR]
    const float* __restrict__ w,   // f32 [NRANK][NE][IPR][HD]
    const int* __restrict__ perm,
    const int* __restrict__ tile_e,
    const int* __restrict__ tile_r0,
    const int* __restrict__ tile_nr,
    const float* __restrict__ gate,
    float* __restrict__ out) {
  // XCD swizzle for W-slice sharing: HW runs blockIdx id on XCD id%8. Remap so
  // XCD c gets the contiguous sw-chunk [c*96, (c+1)*96) with sw = tile*32+nb:
  // 3 consecutive tiles (usually the same expert -> identical W slices) x all
  // 32 n-blocks (sharing each tile's X rows) co-resident per XCD L2.
  const int id = blockIdx.x;
  const int sw = (id & 7) * (NWG / 8) + (id >> 3);
  const int tile = sw >> 5;          // 0..23  (tile-major)
  const int nb   = sw & 31;          // 0..31  (fastest)

  const int e = tile_e[tile];
  if (e < 0) return;
  const int row0 = tile_r0[tile];
  const int nr   = tile_nr[tile];
  const int n0   = nb * BN;

  __shared__ unsigned short Xs[BM][XS];   // bf16 bits, [m][k]  (18 KB)
  __shared__ unsigned short Ws[BN][XS];   // bf16 bits, transposed: [n][k] (9 KB)

  const int tid  = threadIdx.x;
  const int lane = tid & 63;
  const int wid  = tid >> 6;   // 0..3
  const int wr   = wid >> 1;   // 0..1 : 64-row stripe
  const int wc   = wid & 1;    // 0..1 : 32-col stripe

  // ---- X staging coords: 4 passes; 8 threads per row, 32 B (8 f32) each ----
  const int xr = tid >> 3;          // 0..31 (row within pass)
  const int xc = (tid & 7) << 3;    // k-offset 0,8,...,56
  int xtk[4];
#pragma unroll
  for (int p = 0; p < 4; ++p) {
    const int row = p * 32 + xr;
    xtk[p] = (row < nr) ? perm[row0 + row] : -1;
  }

  // ---- W staging coords: one n-column per thread, 16 k-values ----
  const int wn  = tid & 63;          // n within tile (consecutive lanes -> consecutive n)
  const int wkq = (tid >> 6) << 4;   // 0,16,32,48 (k-quarter per wave)

  // single raw-f32 prefetch bank
  float4 xf[4][2];
  float  wv[16];

#define LOADREGS(KT) do {                                                        \
    const int r_  = (KT) >> 10;                                                  \
    const int i0_ = (KT) & 1023;                                                 \
    _Pragma("unroll")                                                            \
    for (int p_ = 0; p_ < 4; ++p_) {                                             \
      if (xtk[p_] >= 0) {                                                        \
        const float* sp_ = x + ((size_t)r_ * TKN + xtk[p_]) * IPR + i0_ + xc;    \
        xf[p_][0] = *reinterpret_cast<const float4*>(sp_);                       \
        xf[p_][1] = *reinterpret_cast<const float4*>(sp_ + 4);                   \
      } else {                                                                   \
        xf[p_][0] = float4{0.f, 0.f, 0.f, 0.f};                                  \
        xf[p_][1] = float4{0.f, 0.f, 0.f, 0.f};                                  \
      }                                                                          \
    }                                                                            \
    const float* wp_ = w + (((size_t)r_ * NE + e) * IPR + i0_ + wkq) * HD + n0 + wn; \
    _Pragma("unroll")                                                            \
    for (int j_ = 0; j_ < 16; ++j_) wv[j_] = wp_[(size_t)j_ * HD];               \
  } while (0)

  f32x4 acc[4][2];
#pragma unroll
  for (int a = 0; a < 4; ++a)
#pragma unroll
    for (int b = 0; b < 2; ++b) acc[a][b] = f32x4{0.f, 0.f, 0.f, 0.f};

  const int lrow = lane & 15;
  const int lk   = (lane >> 4) << 3;   // 0,8,16,24

  LOADREGS(0);

  for (int t = 0; t < NIT; ++t) {
    BAR();   // previous compute's LDS reads drained; LDS free

    // ---- write prefetched regs -> LDS (f32 -> bf16) ----
#pragma unroll
    for (int p = 0; p < 4; ++p) {
      u16x8 v;
      v[0] = f2b(xf[p][0].x); v[1] = f2b(xf[p][0].y);
      v[2] = f2b(xf[p][0].z); v[3] = f2b(xf[p][0].w);
      v[4] = f2b(xf[p][1].x); v[5] = f2b(xf[p][1].y);
      v[6] = f2b(xf[p][1].z); v[7] = f2b(xf[p][1].w);
      *reinterpret_cast<u16x8*>(&Xs[p * 32 + xr][xc]) = v;
    }
    {
      u16x8 a, b;
      a[0] = f2b(wv[0]);  a[1] = f2b(wv[1]);  a[2] = f2b(wv[2]);  a[3] = f2b(wv[3]);
      a[4] = f2b(wv[4]);  a[5] = f2b(wv[5]);  a[6] = f2b(wv[6]);  a[7] = f2b(wv[7]);
      b[0] = f2b(wv[8]);  b[1] = f2b(wv[9]);  b[2] = f2b(wv[10]); b[3] = f2b(wv[11]);
      b[4] = f2b(wv[12]); b[5] = f2b(wv[13]); b[6] = f2b(wv[14]); b[7] = f2b(wv[15]);
      *reinterpret_cast<u16x8*>(&Ws[wn][wkq])     = a;
      *reinterpret_cast<u16x8*>(&Ws[wn][wkq + 8]) = b;
    }
    BAR();   // ds_writes visible to all waves

    // ---- prefetch next iteration (overlaps compute below) ----
    if (t + 1 < NIT) LOADREGS((t + 1) * BK);

    // ---- compute: 2 k-steps of 32, 4x2 fragments per wave ----
#pragma unroll
    for (int ks = 0; ks < 2; ++ks) {
      bf16x8 af[4], bfr[2];
#pragma unroll
      for (int mi = 0; mi < 4; ++mi)
        af[mi] = __builtin_bit_cast(bf16x8,
            *reinterpret_cast<const u16x8*>(&Xs[wr * 64 + mi * 16 + lrow][ks * 32 + lk]));
#pragma unroll
      for (int ni = 0; ni < 2; ++ni)
        bfr[ni] = __builtin_bit_cast(bf16x8,
            *reinterpret_cast<const u16x8*>(&Ws[wc * 32 + ni * 16 + lrow][ks * 32 + lk]));
#pragma unroll
      for (int mi = 0; mi < 4; ++mi)
#pragma unroll
        for (int ni = 0; ni < 2; ++ni)
          acc[mi][ni] = __builtin_amdgcn_mfma_f32_16x16x32_bf16(af[mi], bfr[ni], acc[mi][ni], 0, 0, 0);
    }
  }

  // ---- epilogue: gate * acc, atomicAdd into f32 out (exactly 2 adds/element) ----
  const int mb = (lane >> 4) << 2;
#pragma unroll
  for (int mi = 0; mi < 4; ++mi) {
#pragma unroll
    for (int q = 0; q < 4; ++q) {
      const int m = wr * 64 + mi * 16 + mb + q;
      if (m < nr) {
        const int tk = perm[row0 + m];
        const float g = gate[tk];
        float* dst = out + (size_t)(tk >> 1) * HD + n0 + wc * 32 + lrow;
#pragma unroll
        for (int ni = 0; ni < 2; ++ni)
          atomicAdd(&dst[ni * 16], g * acc[mi][ni][q]);
      }
    }
  }
#undef LOADREGS
}

extern "C" void kernel_launch(void* const* d_in, const int* in_sizes, int n_in,
                              void* d_out, int out_size, void* d_ws, size_t ws_size,
                              hipStream_t stream) {
  const float* x      = (const float*)d_in[0];  // f32 (upcast from fp16)
  const float* w      = (const float*)d_in[1];  // f32 (upcast from fp16)
  const float* logits = (const float*)d_in[2];
  // d_in[3] = topk (constant 2), unused

  char* ws = (char*)d_ws;
  float* gate    = (float*)(ws + 0);          // TKN floats   (8 KB)
  int*   perm    = (int*)(ws + 8192);         // TKN ints     (8 KB)
  int*   tile_e  = (int*)(ws + 16384);        // MAXTILES ints
  int*   tile_r0 = (int*)(ws + 16384 + 256);
  int*   tile_nr = (int*)(ws + 16384 + 512);

  float* outf = (float*)d_out;                // f32 output [NTOK][HD]

  zero_kernel<<<(NTOK * HD / 4) / 256, 256, 0, stream>>>(outf);
  routing_kernel<<<1, 1024, 0, stream>>>(logits, gate, perm, tile_e, tile_r0, tile_nr);
  gemm_kernel<<<NWG, 256, 0, stream>>>(x, w, perm, tile_e, tile_r0, tile_nr, gate, outf);
}